// Round 6
// baseline (520.916 us; speedup 1.0000x reference)
//
#include <hip/hip_runtime.h>

// EGNN layer, round 14b (round-5 was a compile error in the f16-pack helper):
// node_k processes 4 edges/iteration, 16 lanes per edge (lane owns 4 output
// cols). Cuts per-edge wave instructions ~106 -> ~60: gathers batched
// (8B/lane), w2h as uint4 (8 VMEM/edge vs 32), LDS ops /4. fdot2 count
// unchanged (the MAC floor). 1 wave/block kept (r13 showed packing hurts:
// degree-tail imbalance, no occupancy gain).
// B=4, N=16384, E=65536, DH=128, DM=64.  NB = 65536 global nodes.

typedef unsigned short ushort_t;
typedef __attribute__((ext_vector_type(8))) short bf16x8;
typedef __attribute__((ext_vector_type(4))) float f32x4;
typedef _Float16 h2 __attribute__((ext_vector_type(2)));
typedef __fp16 fp16x2 __attribute__((ext_vector_type(2)));

__device__ __forceinline__ float fast_rcp(float v) { return __builtin_amdgcn_rcpf(v); }
__device__ __forceinline__ float fast_silu(float v) { return v * fast_rcp(1.0f + __expf(-v)); }
__device__ __forceinline__ ushort_t f2bf(float f) {
    unsigned u = __float_as_uint(f);
    u += 0x7fffu + ((u >> 16) & 1u);
    return (ushort_t)(u >> 16);
}
__device__ __forceinline__ float bf2f(ushort_t b) {
    return __uint_as_float(((unsigned)b) << 16);
}
__device__ __forceinline__ float bflo(unsigned u) { return __uint_as_float(u << 16); }
__device__ __forceinline__ float bfhi(unsigned u) { return __uint_as_float(u & 0xffff0000u); }
__device__ __forceinline__ h2 u2h2(unsigned u) {
    union { unsigned u; h2 h; } v; v.u = u; return v.h;
}
__device__ __forceinline__ unsigned pk2u(float a, float b) {
    union { fp16x2 h; unsigned u; } v;
    v.h = __builtin_amdgcn_cvt_pkrtz(a, b);
    return v.u;
}

// ---------------------------------------------------------------------------
// init: cursor=0 (65536) + weight transforms. 488*256 = 124928 threads exact.
//  W1t  bf16[128][128] : fused pe_w1 cols, k-contiguous
//  Wp1t bf16[128][192] : ph_w1^T
//  Wp2t bf16[128][128] : ph_w2^T
//  w2h  uint[32][64]   : w2h[k2*64+c] = half2(pe_w2[2k2][c], pe_w2[2k2+1][c])
// ---------------------------------------------------------------------------
__global__ __launch_bounds__(256) void init_k(const float* __restrict__ pe_w1,
                                              const float* __restrict__ pe_w2,
                                              const float* __restrict__ ph_w1,
                                              const float* __restrict__ ph_w2,
                                              int* __restrict__ cursor,
                                              ushort_t* __restrict__ W1t,
                                              ushort_t* __restrict__ Wp1t,
                                              ushort_t* __restrict__ Wp2t,
                                              unsigned* __restrict__ w2h) {
    int gg = blockIdx.x * 256 + threadIdx.x;
    if (gg < 65536) { cursor[gg] = 0; return; }
    int g = gg - 65536;
    if (g < 16384) {
        int c = g >> 7, k = g & 127;
        float v = (c < 64) ? pe_w1[k * 64 + c] : pe_w1[(128 + k) * 64 + (c - 64)];
        W1t[g] = f2bf(v);
    } else if (g < 40960) {
        int g2 = g - 16384;
        int n = g2 / 192, k = g2 - n * 192;
        Wp1t[g2] = f2bf(ph_w1[k * 128 + n]);
    } else if (g < 57344) {
        int g3 = g - 40960;
        int n = g3 >> 7, k = g3 & 127;
        Wp2t[g3] = f2bf(ph_w2[k * 128 + n]);
    } else if (g < 59392) {
        int g4 = g - 57344;
        int k2 = g4 >> 6, c = g4 & 63;
        union { unsigned u; _Float16 h[2]; } p;
        p.h[0] = (_Float16)pe_w2[(2 * k2) * 64 + c];
        p.h[1] = (_Float16)pe_w2[(2 * k2 + 1) * 64 + c];
        w2h[g4] = p.u;
    }
}

// ---------------------------------------------------------------------------
// scatter: elist[gi*64 + slot] = gj  (deg max ~20 << 64)
// ---------------------------------------------------------------------------
__global__ __launch_bounds__(256) void scatter_k(const int* __restrict__ ei,
                                                 int* __restrict__ cursor,
                                                 int* __restrict__ elist) {
    int e = blockIdx.x * 256 + threadIdx.x;
    int2 sd = ((const int2*)ei)[e];
    int b = e >> 16;
    int gi = (b << 14) + sd.x;
    int gj = (b << 14) + sd.y;
    int slot = atomicAdd(&cursor[gi], 1);
    if (slot < 64) elist[gi * 64 + slot] = gj;
}

// ---------------------------------------------------------------------------
// node kernel, round 14: one wave per node; 4 edges per iteration, 16 lanes
// per edge. q = lane&15 owns output cols 4q..4q+3; g = lane>>4 owns edge slot.
// ---------------------------------------------------------------------------
__global__ __launch_bounds__(64, 4) void node_k(const float* __restrict__ x,
                                                const ushort_t* __restrict__ P,
                                                const int* __restrict__ cursor,
                                                const int* __restrict__ elist,
                                                const float* __restrict__ w1,
                                                const float* __restrict__ b1,
                                                const unsigned* __restrict__ w2h,
                                                const float* __restrict__ b2,
                                                const float* __restrict__ pxw,
                                                ushort_t* __restrict__ dh,
                                                float* __restrict__ outx) {
    const int n = blockIdx.x;
    const int lane = threadIdx.x;
    const int q = lane & 15;                 // col-quad: cols 4q..4q+3 (= k 4q..4q+3 in layer 1)
    const int g = lane >> 4;                 // edge group 0..3
    __shared__ __attribute__((aligned(16))) unsigned mlds[4][32];   // [edge][k2] f16 pairs

    // per-lane constants for cols 4q..4q+3
    const float4 w1r4 = *(const float4*)(w1 + 256 * 64 + q * 4);
    const float4 b1v4 = *(const float4*)(b1 + q * 4);
    const float4 b2v4 = *(const float4*)(b2 + q * 4);
    float4 px4 = *(const float4*)(pxw + q * 4);
    px4.x *= 0.0625f; px4.y *= 0.0625f; px4.z *= 0.0625f; px4.w *= 0.0625f;  // fold 16-lane redundancy

    uint2 piu = *(const uint2*)(P + (size_t)n * 128 + q * 4);
    const float pib0 = bflo(piu.x) + b1v4.x;
    const float pib1 = bfhi(piu.x) + b1v4.y;
    const float pib2 = bflo(piu.y) + b1v4.z;
    const float pib3 = bfhi(piu.y) + b1v4.w;

    const float xi0 = x[n * 3 + 0];
    const float xi1 = x[n * 3 + 1];
    const float xi2 = x[n * 3 + 2];

    const int dg = min(cursor[n], 64);
    int gjv = 0;
    if (lane < dg) gjv = elist[n * 64 + lane];   // coalesced adjacency preload

    float dh0 = 0.f, dh1 = 0.f, dh2 = 0.f, dh3 = 0.f;
    float dxp0 = 0.f, dxp1 = 0.f, dxp2 = 0.f;

    const int nt = (dg + 3) >> 2;
    for (int t = 0; t < nt; t++) {
        const int slot = t * 4 + g;
        const int gj = __shfl(gjv, slot);            // group-uniform; 0 for inactive
        const float act = (slot < dg) ? 1.0f : 0.0f;

        // ---- layer 1 for this group's edge, cols 4q..4q+3
        uint2 pj = *(const uint2*)(P + (size_t)gj * 128 + 64 + q * 4);   // 128B/group
        float xj0 = x[gj * 3 + 0];
        float xj1 = x[gj * 3 + 1];
        float xj2 = x[gj * 3 + 2];
        float ddx = xi0 - xj0, ddy = xi1 - xj1, ddz = xi2 - xj2;
        float d2 = fmaxf(ddx * ddx + ddy * ddy + ddz * ddz, 1e-12f);
        float m0 = fast_silu(fmaf(d2, w1r4.x, pib0 + bflo(pj.x)));
        float m1 = fast_silu(fmaf(d2, w1r4.y, pib1 + bfhi(pj.x)));
        float m2v = fast_silu(fmaf(d2, w1r4.z, pib2 + bflo(pj.y)));
        float m3 = fast_silu(fmaf(d2, w1r4.w, pib3 + bfhi(pj.y)));
        // pack to f16 pairs: k2=2q -> (m[4q],m[4q+1]), k2=2q+1 -> (m[4q+2],m[4q+3])
        uint2 mp;
        mp.x = pk2u(m0, m1);
        mp.y = pk2u(m2v, m3);
        __builtin_amdgcn_wave_barrier();
        *(uint2*)&mlds[g][2 * q] = mp;
        __builtin_amdgcn_wave_barrier();

        // ---- layer 2: s[c] = b2[c] + sum_k m[k] W2[k][c], c = 4q..4q+3
        float s0 = b2v4.x, s1 = b2v4.y, s2 = b2v4.z, s3 = b2v4.w;
#pragma unroll
        for (int k8 = 0; k8 < 8; k8++) {
            uint4 mm = *(const uint4*)&mlds[g][k8 * 4];                 // k2 = 4k8..4k8+3 (group bcast)
            uint4 wa = *(const uint4*)(w2h + (4 * k8 + 0) * 64 + q * 4);
            uint4 wb = *(const uint4*)(w2h + (4 * k8 + 1) * 64 + q * 4);
            uint4 wc = *(const uint4*)(w2h + (4 * k8 + 2) * 64 + q * 4);
            uint4 wd = *(const uint4*)(w2h + (4 * k8 + 3) * 64 + q * 4);
            s0 = __builtin_amdgcn_fdot2(u2h2(mm.x), u2h2(wa.x), s0, false);
            s1 = __builtin_amdgcn_fdot2(u2h2(mm.x), u2h2(wa.y), s1, false);
            s2 = __builtin_amdgcn_fdot2(u2h2(mm.x), u2h2(wa.z), s2, false);
            s3 = __builtin_amdgcn_fdot2(u2h2(mm.x), u2h2(wa.w), s3, false);
            s0 = __builtin_amdgcn_fdot2(u2h2(mm.y), u2h2(wb.x), s0, false);
            s1 = __builtin_amdgcn_fdot2(u2h2(mm.y), u2h2(wb.y), s1, false);
            s2 = __builtin_amdgcn_fdot2(u2h2(mm.y), u2h2(wb.z), s2, false);
            s3 = __builtin_amdgcn_fdot2(u2h2(mm.y), u2h2(wb.w), s3, false);
            s0 = __builtin_amdgcn_fdot2(u2h2(mm.z), u2h2(wc.x), s0, false);
            s1 = __builtin_amdgcn_fdot2(u2h2(mm.z), u2h2(wc.y), s1, false);
            s2 = __builtin_amdgcn_fdot2(u2h2(mm.z), u2h2(wc.z), s2, false);
            s3 = __builtin_amdgcn_fdot2(u2h2(mm.z), u2h2(wc.w), s3, false);
            s0 = __builtin_amdgcn_fdot2(u2h2(mm.w), u2h2(wd.x), s0, false);
            s1 = __builtin_amdgcn_fdot2(u2h2(mm.w), u2h2(wd.y), s1, false);
            s2 = __builtin_amdgcn_fdot2(u2h2(mm.w), u2h2(wd.z), s2, false);
            s3 = __builtin_amdgcn_fdot2(u2h2(mm.w), u2h2(wd.w), s3, false);
        }
        __builtin_amdgcn_wave_barrier();

        // ---- epilogue: m2 = silu(s) * act; accumulate dh, mx, dx
        float o0 = fast_silu(s0) * act;
        float o1 = fast_silu(s1) * act;
        float o2 = fast_silu(s2) * act;
        float o3 = fast_silu(s3) * act;
        dh0 += o0; dh1 += o1; dh2 += o2; dh3 += o3;
        float mxp = o0 * px4.x + o1 * px4.y + o2 * px4.z + o3 * px4.w;   // prescaled by 1/16
        mxp += __shfl_xor(mxp, 1);
        mxp += __shfl_xor(mxp, 2);
        mxp += __shfl_xor(mxp, 4);
        mxp += __shfl_xor(mxp, 8);                                       // group total at all 16 lanes
        float cmul = mxp * fast_rcp(sqrtf(d2) + 1e-8f);
        dxp0 = fmaf(cmul, ddx, dxp0);
        dxp1 = fmaf(cmul, ddy, dxp1);
        dxp2 = fmaf(cmul, ddz, dxp2);
    }

    // ---- reduce dh across the 4 groups, write cols 4q..4q+3 from lanes 0..15
    dh0 += __shfl_xor(dh0, 16); dh0 += __shfl_xor(dh0, 32);
    dh1 += __shfl_xor(dh1, 16); dh1 += __shfl_xor(dh1, 32);
    dh2 += __shfl_xor(dh2, 16); dh2 += __shfl_xor(dh2, 32);
    dh3 += __shfl_xor(dh3, 16); dh3 += __shfl_xor(dh3, 32);
    if (g == 0) {
        uint2 dpack;
        dpack.x = (unsigned)f2bf(dh0) | ((unsigned)f2bf(dh1) << 16);
        dpack.y = (unsigned)f2bf(dh2) | ((unsigned)f2bf(dh3) << 16);
        *(uint2*)(dh + (size_t)n * 64 + q * 4) = dpack;                 // 128B coalesced
    }

    // ---- dx reduce over all 64 lanes (16x redundancy folded into px4)
    for (int off = 32; off; off >>= 1) {
        dxp0 += __shfl_down(dxp0, off);
        dxp1 += __shfl_down(dxp1, off);
        dxp2 += __shfl_down(dxp2, off);
    }
    if (lane == 0) {
        outx[n * 3 + 0] = xi0 + dxp0;
        outx[n * 3 + 1] = xi1 + dxp1;
        outx[n * 3 + 2] = xi2 + dxp2;
    }
}

// ---------------------------------------------------------------------------
// P-GEMM: P = h @ [W1_top|W1_mid] (bf16 out), optionally emits hb=bf16(h).
// 128x128 block, 4 waves, 2x8 mfma 16x16x32, KPAD=40.
// ---------------------------------------------------------------------------
template <bool EMIT_BF16>
__global__ __launch_bounds__(256, 2) void pgemm_k(const float* __restrict__ A0,
                                                  const ushort_t* __restrict__ Wt,
                                                  ushort_t* __restrict__ outP,
                                                  ushort_t* __restrict__ hbout) {
    constexpr int KPAD = 40;
    __shared__ ushort_t As[128 * KPAD];
    __shared__ ushort_t Bs[128 * KPAD];
    const int tid = threadIdx.x;
    const int m0 = blockIdx.x * 128;
    const int wave = tid >> 6;
    const int lane = tid & 63;
    const int lr = lane & 15;
    const int lq = lane >> 4;

    f32x4 acc[2][8];
#pragma unroll
    for (int mt = 0; mt < 2; mt++)
#pragma unroll
        for (int nt = 0; nt < 8; nt++) { f32x4 z = {0.f,0.f,0.f,0.f}; acc[mt][nt] = z; }

    for (int k0 = 0; k0 < 128; k0 += 32) {
#pragma unroll
        for (int i = 0; i < 4; i++) {
            int lin = tid + i * 256;
            int m = lin >> 3;
            int kq = (lin & 7) * 4;
            float4 v = *(const float4*)(A0 + (size_t)(m0 + m) * 128 + k0 + kq);
            ushort4 w4;
            w4.x = f2bf(v.x); w4.y = f2bf(v.y); w4.z = f2bf(v.z); w4.w = f2bf(v.w);
            if (EMIT_BF16)
                *(ushort4*)(hbout + (size_t)(m0 + m) * 128 + k0 + kq) = w4;
            *(ushort4*)&As[m * KPAD + kq] = w4;
        }
#pragma unroll
        for (int i = 0; i < 2; i++) {
            int lin = tid + i * 256;
            int n = lin >> 2;
            int kq = (lin & 3) * 8;
            *(uint4*)&Bs[n * KPAD + kq] = *(const uint4*)(Wt + (size_t)n * 128 + k0 + kq);
        }
        __syncthreads();
        bf16x8 af[2], bfr[8];
#pragma unroll
    for (int mt = 0; mt < 2; mt++)
            af[mt] = *(const bf16x8*)&As[(wave * 32 + mt * 16 + lr) * KPAD + lq * 8];
#pragma unroll
        for (int nt = 0; nt < 8; nt++)
            bfr[nt] = *(const bf16x8*)&Bs[(nt * 16 + lr) * KPAD + lq * 8];
#pragma unroll
        for (int mt = 0; mt < 2; mt++)
#pragma unroll
            for (int nt = 0; nt < 8; nt++)
                acc[mt][nt] = __builtin_amdgcn_mfma_f32_16x16x32_bf16(af[mt], bfr[nt], acc[mt][nt], 0, 0, 0);
        __syncthreads();
    }
#pragma unroll
    for (int mt = 0; mt < 2; mt++)
#pragma unroll
        for (int nt = 0; nt < 8; nt++)
#pragma unroll
            for (int r = 0; r < 4; r++) {
                int row = m0 + wave * 32 + mt * 16 + lq * 4 + r;
                int col = nt * 16 + lr;
                outP[(size_t)row * 128 + col] = f2bf(acc[mt][nt][r]);
            }
}

// ---------------------------------------------------------------------------
// Fused node MLP: out_h = h + silu([h|dh]@W1 + b1) @ W2 + b2.
// Phase 1: t(128x128) = silu([h|dh]@W1+b1) -> LDS (bf16, pad 136).
// Phase 2: out = t @ W2 + b2 + h, straight from LDS. No t round-trip to HBM.
// ---------------------------------------------------------------------------
template <bool USE_HB>
__global__ __launch_bounds__(256, 2) void mlp_fused_k(const float* __restrict__ h,
                                                      const ushort_t* __restrict__ hb,
                                                      const ushort_t* __restrict__ dh,
                                                      const ushort_t* __restrict__ Wp1t,
                                                      const float* __restrict__ b1,
                                                      const ushort_t* __restrict__ Wp2t,
                                                      const float* __restrict__ b2,
                                                      float* __restrict__ outh) {
    constexpr int KPAD = 40, TPAD = 136;
    __shared__ ushort_t As[128 * KPAD];
    __shared__ ushort_t Bs[128 * KPAD];
    __shared__ ushort_t Ts[128 * TPAD];
    const int tid = threadIdx.x;
    const int m0 = blockIdx.x * 128;
    const int wave = tid >> 6;
    const int lane = tid & 63;
    const int lr = lane & 15;
    const int lq = lane >> 4;

    f32x4 acc[2][8];
#pragma unroll
    for (int mt = 0; mt < 2; mt++)
#pragma unroll
        for (int nt = 0; nt < 8; nt++) { f32x4 z = {0.f,0.f,0.f,0.f}; acc[mt][nt] = z; }

    // ---- phase 1: t = silu([h|dh] @ W1 + b1), K = 192
    for (int k0 = 0; k0 < 192; k0 += 32) {
        if (USE_HB) {
#pragma unroll
            for (int i = 0; i < 2; i++) {
                int lin = tid + i * 256;
                int m = lin >> 2;
                int kq = (lin & 3) * 8;
                const ushort_t* src = (k0 >= 128)
                    ? dh + (size_t)(m0 + m) * 64 + (k0 - 128 + kq)
                    : hb + (size_t)(m0 + m) * 128 + k0 + kq;
                *(uint4*)&As[m * KPAD + kq] = *(const uint4*)src;
            }
        } else {
#pragma unroll
            for (int i = 0; i < 4; i++) {
                int lin = tid + i * 256;
                int m = lin >> 3;
                int kq = (lin & 7) * 4;
                ushort4 w4;
                if (k0 >= 128) {
                    w4 = *(const ushort4*)(dh + (size_t)(m0 + m) * 64 + (k0 - 128 + kq));
                } else {
                    float4 v = *(const float4*)(h + (size_t)(m0 + m) * 128 + k0 + kq);
                    w4.x = f2bf(v.x); w4.y = f2bf(v.y); w4.z = f2bf(v.z); w4.w = f2bf(v.w);
                }
                *(ushort4*)&As[m * KPAD + kq] = w4;
            }
        }
#pragma unroll
        for (int i = 0; i < 2; i++) {
            int lin = tid + i * 256;
            int n = lin >> 2;
            int kq = (lin & 3) * 8;
            *(uint4*)&Bs[n * KPAD + kq] = *(const uint4*)(Wp1t + (size_t)n * 192 + k0 + kq);
        }
        __syncthreads();
        bf16x8 af[2], bfr[8];
#pragma unroll
        for (int mt = 0; mt < 2; mt++)
            af[mt] = *(const bf16x8*)&As[(wave * 32 + mt * 16 + lr) * KPAD + lq * 8];
#pragma unroll
        for (int nt = 0; nt < 8; nt++)
            bfr[nt] = *(const bf16x8*)&Bs[(nt * 16 + lr) * KPAD + lq * 8];
#pragma unroll
        for (int mt = 0; mt < 2; mt++)
#pragma unroll
            for (int nt = 0; nt < 8; nt++)
                acc[mt][nt] = __builtin_amdgcn_mfma_f32_16x16x32_bf16(af[mt], bfr[nt], acc[mt][nt], 0, 0, 0);
        __syncthreads();
    }
    // epilogue 1: silu -> Ts (bf16)
#pragma unroll
    for (int mt = 0; mt < 2; mt++)
#pragma unroll
        for (int nt = 0; nt < 8; nt++)
#pragma unroll
            for (int r = 0; r < 4; r++) {
                int row = wave * 32 + mt * 16 + lq * 4 + r;
                int col = nt * 16 + lr;
                Ts[row * TPAD + col] = f2bf(fast_silu(acc[mt][nt][r] + b1[col]));
            }
    __syncthreads();

    // ---- phase 2: out = t @ W2 + b2 + h, K = 128, A from Ts
    f32x4 acc2[2][8];
#pragma unroll
    for (int mt = 0; mt < 2; mt++)
#pragma unroll
        for (int nt = 0; nt < 8; nt++) { f32x4 z = {0.f,0.f,0.f,0.f}; acc2[mt][nt] = z; }

    for (int k0 = 0; k0 < 128; k0 += 32) {
#pragma unroll
        for (int i = 0; i < 2; i++) {
            int lin = tid + i * 256;
            int n = lin >> 2;
            int kq = (lin & 3) * 8;
            *(uint4*)&Bs[n * KPAD + kq] = *(const uint4*)(Wp2t + (size_t)n * 128 + k0 + kq);
        }
        __syncthreads();
        bf16x8 af[2], bfr[8];
#pragma unroll
        for (int mt = 0; mt < 2; mt++)
            af[mt] = *(const bf16x8*)&Ts[(wave * 32 + mt * 16 + lr) * TPAD + k0 + lq * 8];
#pragma unroll
        for (int nt = 0; nt < 8; nt++)
            bfr[nt] = *(const bf16x8*)&Bs[(nt * 16 + lr) * KPAD + lq * 8];
#pragma unroll
        for (int mt = 0; mt < 2; mt++)
#pragma unroll
            for (int nt = 0; nt < 8; nt++)
                acc2[mt][nt] = __builtin_amdgcn_mfma_f32_16x16x32_bf16(af[mt], bfr[nt], acc2[mt][nt], 0, 0, 0);
        __syncthreads();
    }
    // epilogue 2: + b2 + h residual
#pragma unroll
    for (int mt = 0; mt < 2; mt++)
#pragma unroll
        for (int nt = 0; nt < 8; nt++)
#pragma unroll
            for (int r = 0; r < 4; r++) {
                int row = m0 + wave * 32 + mt * 16 + lq * 4 + r;
                int col = nt * 16 + lr;
                float v = acc2[mt][nt][r] + b2[col];
                if (USE_HB) v += bf2f(hb[(size_t)row * 128 + col]);
                else        v += h[(size_t)row * 128 + col];
                outh[(size_t)row * 128 + col] = v;
            }
}

// ---------------------------------------------------------------------------
extern "C" void kernel_launch(void* const* d_in, const int* in_sizes, int n_in,
                              void* d_out, int out_size, void* d_ws, size_t ws_size,
                              hipStream_t stream) {
    const float* x     = (const float*)d_in[0];
    const float* h     = (const float*)d_in[1];
    const int*   ei    = (const int*)d_in[2];
    const float* pe_w1 = (const float*)d_in[3];
    const float* pe_b1 = (const float*)d_in[4];
    const float* pe_w2 = (const float*)d_in[5];
    const float* pe_b2 = (const float*)d_in[6];
    const float* px_w  = (const float*)d_in[7];
    const float* ph_w1 = (const float*)d_in[8];
    const float* ph_b1 = (const float*)d_in[9];
    const float* ph_w2 = (const float*)d_in[10];
    const float* ph_b2 = (const float*)d_in[11];

    float* outx = (float*)d_out;                    // 4*16384*3
    float* outh = (float*)d_out + 196608;           // 4*16384*128

    // ws layout
    ushort_t* P    = (ushort_t*)d_ws;                     // 65536*128 bf16
    ushort_t* dh   = P + (size_t)65536 * 128;             // 65536*64 bf16
    int* cursor    = (int*)(dh + (size_t)65536 * 64);     // 65536 i32
    int* elist     = cursor + 65536;                      // 65536*64 i32 (16 MB)
    ushort_t* W1t  = (ushort_t*)(elist + (size_t)65536 * 64);  // 128*128 bf16
    ushort_t* Wp1t = W1t + 16384;                         // 128*192 bf16
    ushort_t* Wp2t = Wp1t + 24576;                        // 128*128 bf16
    unsigned* w2h  = (unsigned*)(Wp2t + 16384);           // 32*64 uint (in 16KB slot)
    ushort_t* hb   = (ushort_t*)(w2h + 4096);             // 65536*128 bf16 (16 MB)
    size_t need_hb = (size_t)((char*)(hb + (size_t)65536 * 128) - (char*)d_ws);
    const bool use_hb = ws_size >= need_hb;

    init_k<<<488, 256, 0, stream>>>(pe_w1, pe_w2, ph_w1, ph_w2,
                                    cursor, W1t, Wp1t, Wp2t, w2h);
    if (use_hb)
        pgemm_k<true><<<512, 256, 0, stream>>>(h, W1t, P, hb);
    else
        pgemm_k<false><<<512, 256, 0, stream>>>(h, W1t, P, nullptr);
    scatter_k<<<1024, 256, 0, stream>>>(ei, cursor, elist);
    node_k<<<65536, 64, 0, stream>>>(x, P, cursor, elist,
                                     pe_w1, pe_b1, w2h, pe_b2, px_w,
                                     dh, outx);
    if (use_hb)
        mlp_fused_k<true><<<512, 256, 0, stream>>>(h, hb, dh, Wp1t, ph_b1,
                                                   Wp2t, ph_b2, outh);
    else
        mlp_fused_k<false><<<512, 256, 0, stream>>>(h, nullptr, dh, Wp1t, ph_b1,
                                                    Wp2t, ph_b2, outh);
}

// Round 8
// 193.868 us; speedup vs baseline: 2.6870x; 2.6870x over previous
//
#include <hip/hip_runtime.h>

// EGNN layer, round 16: r15 minus the inline-asm cvt_pk (it produced NaN in P;
// reverted to the proven bit-twiddle f2bf everywhere). Keeps the single change
// under test: node_k register prefetch of next edge's Pj/x gather, hiding L2
// latency under the current edge's 32-fdot2 chain.
// B=4, N=16384, E=65536, DH=128, DM=64.  NB = 65536 global nodes.

typedef unsigned short ushort_t;
typedef __attribute__((ext_vector_type(8))) short bf16x8;
typedef __attribute__((ext_vector_type(4))) float f32x4;
typedef _Float16 h2 __attribute__((ext_vector_type(2)));

__device__ __forceinline__ float fast_rcp(float v) { return __builtin_amdgcn_rcpf(v); }
__device__ __forceinline__ float fast_silu(float v) { return v * fast_rcp(1.0f + __expf(-v)); }
__device__ __forceinline__ ushort_t f2bf(float f) {
    unsigned u = __float_as_uint(f);
    u += 0x7fffu + ((u >> 16) & 1u);
    return (ushort_t)(u >> 16);
}
__device__ __forceinline__ float bf2f(ushort_t b) {
    return __uint_as_float(((unsigned)b) << 16);
}
__device__ __forceinline__ h2 u2h2(unsigned u) {
    union { unsigned u; h2 h; } v; v.u = u; return v.h;
}

// ---------------------------------------------------------------------------
// init: cursor=0 (65536) + weight transforms. 488*256 = 124928 threads exact.
//  W1t  bf16[128][128] : fused pe_w1 cols, k-contiguous
//  Wp1t bf16[128][192] : ph_w1^T
//  Wp2t bf16[128][128] : ph_w2^T
//  w2h  uint[32][64]   : w2h[k2*64+c] = half2(pe_w2[2k2][c], pe_w2[2k2+1][c])
// ---------------------------------------------------------------------------
__global__ __launch_bounds__(256) void init_k(const float* __restrict__ pe_w1,
                                              const float* __restrict__ pe_w2,
                                              const float* __restrict__ ph_w1,
                                              const float* __restrict__ ph_w2,
                                              int* __restrict__ cursor,
                                              ushort_t* __restrict__ W1t,
                                              ushort_t* __restrict__ Wp1t,
                                              ushort_t* __restrict__ Wp2t,
                                              unsigned* __restrict__ w2h) {
    int gg = blockIdx.x * 256 + threadIdx.x;
    if (gg < 65536) { cursor[gg] = 0; return; }
    int g = gg - 65536;
    if (g < 16384) {
        int c = g >> 7, k = g & 127;
        float v = (c < 64) ? pe_w1[k * 64 + c] : pe_w1[(128 + k) * 64 + (c - 64)];
        W1t[g] = f2bf(v);
    } else if (g < 40960) {
        int g2 = g - 16384;
        int n = g2 / 192, k = g2 - n * 192;
        Wp1t[g2] = f2bf(ph_w1[k * 128 + n]);
    } else if (g < 57344) {
        int g3 = g - 40960;
        int n = g3 >> 7, k = g3 & 127;
        Wp2t[g3] = f2bf(ph_w2[k * 128 + n]);
    } else if (g < 59392) {
        int g4 = g - 57344;
        int k2 = g4 >> 6, c = g4 & 63;
        union { unsigned u; _Float16 h[2]; } p;
        p.h[0] = (_Float16)pe_w2[(2 * k2) * 64 + c];
        p.h[1] = (_Float16)pe_w2[(2 * k2 + 1) * 64 + c];
        w2h[g4] = p.u;
    }
}

// ---------------------------------------------------------------------------
// scatter: elist[gi*64 + slot] = gj  (deg max ~20 << 64)
// ---------------------------------------------------------------------------
__global__ __launch_bounds__(256) void scatter_k(const int* __restrict__ ei,
                                                 int* __restrict__ cursor,
                                                 int* __restrict__ elist) {
    int e = blockIdx.x * 256 + threadIdx.x;
    int2 sd = ((const int2*)ei)[e];
    int b = e >> 16;
    int gi = (b << 14) + sd.x;
    int gj = (b << 14) + sd.y;
    int slot = atomicAdd(&cursor[gi], 1);
    if (slot < 64) elist[gi * 64 + slot] = gj;
}

// ---------------------------------------------------------------------------
// node kernel, round 16: r11 proven loop (one wave per node, lane = feature)
// + register prefetch of next edge's Pj/x gather so the L2 latency hides
// under the current edge's 32-fdot2 chain.
// ---------------------------------------------------------------------------
__global__ __launch_bounds__(64, 4) void node_k(const float* __restrict__ x,
                                                const ushort_t* __restrict__ P,
                                                const int* __restrict__ cursor,
                                                const int* __restrict__ elist,
                                                const float* __restrict__ w1,
                                                const float* __restrict__ b1,
                                                const unsigned* __restrict__ w2h,
                                                const float* __restrict__ b2,
                                                const float* __restrict__ pxw,
                                                ushort_t* __restrict__ dh,
                                                float* __restrict__ outx) {
    const int n = blockIdx.x;
    const int lane = threadIdx.x;
    __shared__ __attribute__((aligned(16))) unsigned m_u[32];    // 64 halves
    ushort_t* mh = (ushort_t*)m_u;

    const float w1r = w1[256 * 64 + lane];       // dist2 row of pe_w1
    const float b2v = b2[lane];
    const float pxv = pxw[lane];
    const float Pib = bf2f(P[(size_t)n * 128 + lane]) + b1[lane];
    const float xi0 = x[n * 3 + 0];
    const float xi1 = x[n * 3 + 1];
    const float xi2 = x[n * 3 + 2];

    float dhacc = 0.0f;
    float dxp0 = 0.0f, dxp1 = 0.0f, dxp2 = 0.0f;
    const int dg = min(cursor[n], 64);
    const int base = n * 64;

    // prefetch edge 0 (gj=0 row is valid memory when dg==0; loop then skips)
    int gj0 = (dg > 0) ? elist[base] : 0;
    float Pj = bf2f(P[(size_t)gj0 * 128 + 64 + lane]);
    float xj0 = x[gj0 * 3 + 0];
    float xj1 = x[gj0 * 3 + 1];
    float xj2 = x[gj0 * 3 + 2];

    for (int t = 0; t < dg; t++) {
        // issue next edge's gather before this edge's dot chain
        int gjn = (t + 1 < dg) ? elist[base + t + 1] : 0;
        float Pjn = bf2f(P[(size_t)gjn * 128 + 64 + lane]);
        float xn0 = x[gjn * 3 + 0];
        float xn1 = x[gjn * 3 + 1];
        float xn2 = x[gjn * 3 + 2];

        float ddx = xi0 - xj0;
        float ddy = xi1 - xj1;
        float ddz = xi2 - xj2;
        float d2 = fmaxf(ddx * ddx + ddy * ddy + ddz * ddz, 1e-12f);
        float m = fast_silu(Pib + Pj + d2 * w1r);
        __builtin_amdgcn_wave_barrier();
        union { ushort_t s; _Float16 h; } mc;
        mc.h = (_Float16)m;
        mh[lane] = mc.s;
        __builtin_amdgcn_wave_barrier();
        float s0 = b2v, s1 = 0.0f, s2 = 0.0f, s3 = 0.0f;
#pragma unroll
        for (int q = 0; q < 8; q++) {
            uint4 mm = *(const uint4*)&m_u[q * 4];               // ds_read_b128 broadcast
            s0 = __builtin_amdgcn_fdot2(u2h2(mm.x), u2h2(w2h[(4 * q + 0) * 64 + lane]), s0, false);
            s1 = __builtin_amdgcn_fdot2(u2h2(mm.y), u2h2(w2h[(4 * q + 1) * 64 + lane]), s1, false);
            s2 = __builtin_amdgcn_fdot2(u2h2(mm.z), u2h2(w2h[(4 * q + 2) * 64 + lane]), s2, false);
            s3 = __builtin_amdgcn_fdot2(u2h2(mm.w), u2h2(w2h[(4 * q + 3) * 64 + lane]), s3, false);
        }
        __builtin_amdgcn_wave_barrier();
        float m2 = fast_silu((s0 + s1) + (s2 + s3));
        dhacc += m2;
        float c = m2 * pxv * fast_rcp(sqrtf(d2) + 1e-8f);
        dxp0 = fmaf(c, ddx, dxp0);
        dxp1 = fmaf(c, ddy, dxp1);
        dxp2 = fmaf(c, ddz, dxp2);

        Pj = Pjn; xj0 = xn0; xj1 = xn1; xj2 = xn2;
    }

    dh[(size_t)n * 64 + lane] = f2bf(dhacc);                 // coalesced

    for (int off = 32; off; off >>= 1) {
        dxp0 += __shfl_down(dxp0, off);
        dxp1 += __shfl_down(dxp1, off);
        dxp2 += __shfl_down(dxp2, off);
    }
    if (lane == 0) {
        outx[n * 3 + 0] = xi0 + dxp0;
        outx[n * 3 + 1] = xi1 + dxp1;
        outx[n * 3 + 2] = xi2 + dxp2;
    }
}

// ---------------------------------------------------------------------------
// P-GEMM: P = h @ [W1_top|W1_mid] (bf16 out), optionally emits hb=bf16(h).
// 128x128 block, 4 waves, 2x8 mfma 16x16x32, KPAD=40.
// ---------------------------------------------------------------------------
template <bool EMIT_BF16>
__global__ __launch_bounds__(256, 2) void pgemm_k(const float* __restrict__ A0,
                                                  const ushort_t* __restrict__ Wt,
                                                  ushort_t* __restrict__ outP,
                                                  ushort_t* __restrict__ hbout) {
    constexpr int KPAD = 40;
    __shared__ ushort_t As[128 * KPAD];
    __shared__ ushort_t Bs[128 * KPAD];
    const int tid = threadIdx.x;
    const int m0 = blockIdx.x * 128;
    const int wave = tid >> 6;
    const int lane = tid & 63;
    const int lr = lane & 15;
    const int lq = lane >> 4;

    f32x4 acc[2][8];
#pragma unroll
    for (int mt = 0; mt < 2; mt++)
#pragma unroll
        for (int nt = 0; nt < 8; nt++) { f32x4 z = {0.f,0.f,0.f,0.f}; acc[mt][nt] = z; }

    for (int k0 = 0; k0 < 128; k0 += 32) {
#pragma unroll
        for (int i = 0; i < 4; i++) {
            int lin = tid + i * 256;
            int m = lin >> 3;
            int kq = (lin & 7) * 4;
            float4 v = *(const float4*)(A0 + (size_t)(m0 + m) * 128 + k0 + kq);
            ushort4 w4;
            w4.x = f2bf(v.x); w4.y = f2bf(v.y); w4.z = f2bf(v.z); w4.w = f2bf(v.w);
            if (EMIT_BF16)
                *(ushort4*)(hbout + (size_t)(m0 + m) * 128 + k0 + kq) = w4;
            *(ushort4*)&As[m * KPAD + kq] = w4;
        }
#pragma unroll
        for (int i = 0; i < 2; i++) {
            int lin = tid + i * 256;
            int n = lin >> 2;
            int kq = (lin & 3) * 8;
            *(uint4*)&Bs[n * KPAD + kq] = *(const uint4*)(Wt + (size_t)n * 128 + k0 + kq);
        }
        __syncthreads();
        bf16x8 af[2], bfr[8];
#pragma unroll
        for (int mt = 0; mt < 2; mt++)
            af[mt] = *(const bf16x8*)&As[(wave * 32 + mt * 16 + lr) * KPAD + lq * 8];
#pragma unroll
        for (int nt = 0; nt < 8; nt++)
            bfr[nt] = *(const bf16x8*)&Bs[(nt * 16 + lr) * KPAD + lq * 8];
#pragma unroll
        for (int mt = 0; mt < 2; mt++)
#pragma unroll
            for (int nt = 0; nt < 8; nt++)
                acc[mt][nt] = __builtin_amdgcn_mfma_f32_16x16x32_bf16(af[mt], bfr[nt], acc[mt][nt], 0, 0, 0);
        __syncthreads();
    }
#pragma unroll
    for (int mt = 0; mt < 2; mt++)
#pragma unroll
        for (int nt = 0; nt < 8; nt++)
#pragma unroll
            for (int r = 0; r < 4; r++) {
                int row = m0 + wave * 32 + mt * 16 + lq * 4 + r;
                int col = nt * 16 + lr;
                outP[(size_t)row * 128 + col] = f2bf(acc[mt][nt][r]);
            }
}

// ---------------------------------------------------------------------------
// Fused node MLP: out_h = h + silu([h|dh]@W1 + b1) @ W2 + b2.
// Phase 1: t(128x128) = silu([h|dh]@W1+b1) -> LDS (bf16, pad 136).
// Phase 2: out = t @ W2 + b2 + h, straight from LDS. No t round-trip to HBM.
// ---------------------------------------------------------------------------
template <bool USE_HB>
__global__ __launch_bounds__(256, 2) void mlp_fused_k(const float* __restrict__ h,
                                                      const ushort_t* __restrict__ hb,
                                                      const ushort_t* __restrict__ dh,
                                                      const ushort_t* __restrict__ Wp1t,
                                                      const float* __restrict__ b1,
                                                      const ushort_t* __restrict__ Wp2t,
                                                      const float* __restrict__ b2,
                                                      float* __restrict__ outh) {
    constexpr int KPAD = 40, TPAD = 136;
    __shared__ ushort_t As[128 * KPAD];
    __shared__ ushort_t Bs[128 * KPAD];
    __shared__ ushort_t Ts[128 * TPAD];
    const int tid = threadIdx.x;
    const int m0 = blockIdx.x * 128;
    const int wave = tid >> 6;
    const int lane = tid & 63;
    const int lr = lane & 15;
    const int lq = lane >> 4;

    f32x4 acc[2][8];
#pragma unroll
    for (int mt = 0; mt < 2; mt++)
#pragma unroll
        for (int nt = 0; nt < 8; nt++) { f32x4 z = {0.f,0.f,0.f,0.f}; acc[mt][nt] = z; }

    // ---- phase 1: t = silu([h|dh] @ W1 + b1), K = 192
    for (int k0 = 0; k0 < 192; k0 += 32) {
        if (USE_HB) {
#pragma unroll
            for (int i = 0; i < 2; i++) {
                int lin = tid + i * 256;
                int m = lin >> 2;
                int kq = (lin & 3) * 8;
                const ushort_t* src = (k0 >= 128)
                    ? dh + (size_t)(m0 + m) * 64 + (k0 - 128 + kq)
                    : hb + (size_t)(m0 + m) * 128 + k0 + kq;
                *(uint4*)&As[m * KPAD + kq] = *(const uint4*)src;
            }
        } else {
#pragma unroll
            for (int i = 0; i < 4; i++) {
                int lin = tid + i * 256;
                int m = lin >> 3;
                int kq = (lin & 7) * 4;
                ushort4 w4;
                if (k0 >= 128) {
                    w4 = *(const ushort4*)(dh + (size_t)(m0 + m) * 64 + (k0 - 128 + kq));
                } else {
                    float4 v = *(const float4*)(h + (size_t)(m0 + m) * 128 + k0 + kq);
                    w4.x = f2bf(v.x); w4.y = f2bf(v.y); w4.z = f2bf(v.z); w4.w = f2bf(v.w);
                }
                *(ushort4*)&As[m * KPAD + kq] = w4;
            }
        }
#pragma unroll
        for (int i = 0; i < 2; i++) {
            int lin = tid + i * 256;
            int n = lin >> 2;
            int kq = (lin & 3) * 8;
            *(uint4*)&Bs[n * KPAD + kq] = *(const uint4*)(Wp1t + (size_t)n * 192 + k0 + kq);
        }
        __syncthreads();
        bf16x8 af[2], bfr[8];
#pragma unroll
        for (int mt = 0; mt < 2; mt++)
            af[mt] = *(const bf16x8*)&As[(wave * 32 + mt * 16 + lr) * KPAD + lq * 8];
#pragma unroll
        for (int nt = 0; nt < 8; nt++)
            bfr[nt] = *(const bf16x8*)&Bs[(nt * 16 + lr) * KPAD + lq * 8];
#pragma unroll
        for (int mt = 0; mt < 2; mt++)
#pragma unroll
            for (int nt = 0; nt < 8; nt++)
                acc[mt][nt] = __builtin_amdgcn_mfma_f32_16x16x32_bf16(af[mt], bfr[nt], acc[mt][nt], 0, 0, 0);
        __syncthreads();
    }
    // epilogue 1: silu -> Ts (bf16)
#pragma unroll
    for (int mt = 0; mt < 2; mt++)
#pragma unroll
        for (int nt = 0; nt < 8; nt++)
#pragma unroll
            for (int r = 0; r < 4; r++) {
                int row = wave * 32 + mt * 16 + lq * 4 + r;
                int col = nt * 16 + lr;
                Ts[row * TPAD + col] = f2bf(fast_silu(acc[mt][nt][r] + b1[col]));
            }
    __syncthreads();

    // ---- phase 2: out = t @ W2 + b2 + h, K = 128, A from Ts
    f32x4 acc2[2][8];
#pragma unroll
    for (int mt = 0; mt < 2; mt++)
#pragma unroll
        for (int nt = 0; nt < 8; nt++) { f32x4 z = {0.f,0.f,0.f,0.f}; acc2[mt][nt] = z; }

    for (int k0 = 0; k0 < 128; k0 += 32) {
#pragma unroll
        for (int i = 0; i < 2; i++) {
            int lin = tid + i * 256;
            int n = lin >> 2;
            int kq = (lin & 3) * 8;
            *(uint4*)&Bs[n * KPAD + kq] = *(const uint4*)(Wp2t + (size_t)n * 128 + k0 + kq);
        }
        __syncthreads();
        bf16x8 af[2], bfr[8];
#pragma unroll
        for (int mt = 0; mt < 2; mt++)
            af[mt] = *(const bf16x8*)&Ts[(wave * 32 + mt * 16 + lr) * TPAD + k0 + lq * 8];
#pragma unroll
        for (int nt = 0; nt < 8; nt++)
            bfr[nt] = *(const bf16x8*)&Bs[(nt * 16 + lr) * KPAD + lq * 8];
#pragma unroll
        for (int mt = 0; mt < 2; mt++)
#pragma unroll
            for (int nt = 0; nt < 8; nt++)
                acc2[mt][nt] = __builtin_amdgcn_mfma_f32_16x16x32_bf16(af[mt], bfr[nt], acc2[mt][nt], 0, 0, 0);
        __syncthreads();
    }
    // epilogue 2: + b2 + h residual
#pragma unroll
    for (int mt = 0; mt < 2; mt++)
#pragma unroll
        for (int nt = 0; nt < 8; nt++)
#pragma unroll
            for (int r = 0; r < 4; r++) {
                int row = m0 + wave * 32 + mt * 16 + lq * 4 + r;
                int col = nt * 16 + lr;
                float v = acc2[mt][nt][r] + b2[col];
                if (USE_HB) v += bf2f(hb[(size_t)row * 128 + col]);
                else        v += h[(size_t)row * 128 + col];
                outh[(size_t)row * 128 + col] = v;
            }
}

// ---------------------------------------------------------------------------
extern "C" void kernel_launch(void* const* d_in, const int* in_sizes, int n_in,
                              void* d_out, int out_size, void* d_ws, size_t ws_size,
                              hipStream_t stream) {
    const float* x     = (const float*)d_in[0];
    const float* h     = (const float*)d_in[1];
    const int*   ei    = (const int*)d_in[2];
    const float* pe_w1 = (const float*)d_in[3];
    const float* pe_b1 = (const float*)d_in[4];
    const float* pe_w2 = (const float*)d_in[5];
    const float* pe_b2 = (const float*)d_in[6];
    const float* px_w  = (const float*)d_in[7];
    const float* ph_w1 = (const float*)d_in[8];
    const float* ph_b1 = (const float*)d_in[9];
    const float* ph_w2 = (const float*)d_in[10];
    const float* ph_b2 = (const float*)d_in[11];

    float* outx = (float*)d_out;                    // 4*16384*3
    float* outh = (float*)d_out + 196608;           // 4*16384*128

    // ws layout
    ushort_t* P    = (ushort_t*)d_ws;                     // 65536*128 bf16
    ushort_t* dh   = P + (size_t)65536 * 128;             // 65536*64 bf16
    int* cursor    = (int*)(dh + (size_t)65536 * 64);     // 65536 i32
    int* elist     = cursor + 65536;                      // 65536*64 i32 (16 MB)
    ushort_t* W1t  = (ushort_t*)(elist + (size_t)65536 * 64);  // 128*128 bf16
    ushort_t* Wp1t = W1t + 16384;                         // 128*192 bf16
    ushort_t* Wp2t = Wp1t + 24576;                        // 128*128 bf16
    unsigned* w2h  = (unsigned*)(Wp2t + 16384);           // 32*64 uint (in 16KB slot)
    ushort_t* hb   = (ushort_t*)(w2h + 4096);             // 65536*128 bf16 (16 MB)
    size_t need_hb = (size_t)((char*)(hb + (size_t)65536 * 128) - (char*)d_ws);
    const bool use_hb = ws_size >= need_hb;

    init_k<<<488, 256, 0, stream>>>(pe_w1, pe_w2, ph_w1, ph_w2,
                                    cursor, W1t, Wp1t, Wp2t, w2h);
    if (use_hb)
        pgemm_k<true><<<512, 256, 0, stream>>>(h, W1t, P, hb);
    else
        pgemm_k<false><<<512, 256, 0, stream>>>(h, W1t, P, nullptr);
    scatter_k<<<1024, 256, 0, stream>>>(ei, cursor, elist);
    node_k<<<65536, 64, 0, stream>>>(x, P, cursor, elist,
                                     pe_w1, pe_b1, w2h, pe_b2, px_w,
                                     dh, outx);
    if (use_hb)
        mlp_fused_k<true><<<512, 256, 0, stream>>>(h, hb, dh, Wp1t, ph_b1,
                                                   Wp2t, ph_b2, outh);
    else
        mlp_fused_k<false><<<512, 256, 0, stream>>>(h, nullptr, dh, Wp1t, ph_b1,
                                                    Wp2t, ph_b2, outh);
}